// Round 4
// baseline (200.668 us; speedup 1.0000x reference)
//
#include <hip/hip_runtime.h>
#include <hip/hip_bf16.h>
#include <stdint.h>

typedef __bf16 bf16x8 __attribute__((ext_vector_type(8)));
typedef float f32x4 __attribute__((ext_vector_type(4)));

#define T_SEQ 4096
#define C_DIM 1024
#define H_NUM 16
#define HD 64
#define C3 3072
#define NEG_BIG (-30000.0f)

__device__ __forceinline__ unsigned short f2bf(float f) {
    uint32_t u = __builtin_bit_cast(uint32_t, f);
    u += 0x7fffu + ((u >> 16) & 1u);
    return (unsigned short)(u >> 16);
}

__device__ __forceinline__ uint32_t pk_bf16(float a, float b) {
    __hip_bfloat162 h = __float22bfloat162_rn(float2{a, b});
    uint32_t u;
    __builtin_memcpy(&u, &h, sizeof(u));
    return u;
}

__device__ __forceinline__ bf16x8 ld_bf8(const unsigned short* p) {
    return *reinterpret_cast<const bf16x8*>(p);
}

__device__ __forceinline__ void async_g2l16(const unsigned short* g, unsigned short* l) {
    __builtin_amdgcn_global_load_lds(
        (const __attribute__((address_space(1))) void*)g,
        (__attribute__((address_space(3))) void*)l, 16, 0, 0);
}

__device__ __forceinline__ void store_c(unsigned short* C, size_t idx, float v) { C[idx] = f2bf(v); }
__device__ __forceinline__ void store_c(float* C, size_t idx, float v)          { C[idx] = v; }

__device__ __forceinline__ void cvt8(const float* src, unsigned short* dst) {
    float4 f0 = *(const float4*)src;
    float4 f1 = *(const float4*)(src + 4);
    union { uint32_t w[4]; uint4 q; } t;
    t.w[0] = pk_bf16(f0.x, f0.y);
    t.w[1] = pk_bf16(f0.z, f0.w);
    t.w[2] = pk_bf16(f1.x, f1.y);
    t.w[3] = pk_bf16(f1.z, f1.w);
    *(uint4*)dst = t.q;
}

// x and w_attn fp32 -> bf16 in one launch (concatenated index space)
__global__ void cvt_xw(const float* __restrict__ x, const float* __restrict__ wa,
                       unsigned short* __restrict__ xb, unsigned short* __restrict__ wab) {
    int i = (blockIdx.x * blockDim.x + threadIdx.x) * 8;
    if (i < T_SEQ * C_DIM) cvt8(x + i, xb + i);
    else {
        int k = i - T_SEQ * C_DIM;
        if (k < C3 * C_DIM) cvt8(wa + k, wab + k);
    }
}

__global__ void cvt_f32_bf16(const float* __restrict__ src, unsigned short* __restrict__ dst, int n) {
    int i = (blockIdx.x * blockDim.x + threadIdx.x) * 8;
    if (i >= n) return;
    cvt8(src + i, dst + i);
}

// V part of qkv [T][3C] -> Vt [C][T], 64x64 tiles through padded LDS.
__global__ __launch_bounds__(256) void v_transpose(
    const unsigned short* __restrict__ qkv, unsigned short* __restrict__ Vt)
{
    __shared__ unsigned short tile[64][72];
    const int t0 = blockIdx.x * 64, c0 = blockIdx.y * 64;
    const int r = threadIdx.x >> 2, q = threadIdx.x & 3;

    const unsigned short* src = qkv + (size_t)(t0 + r) * C3 + 2 * C_DIM + c0 + q * 16;
    *(uint4*)&tile[r][q * 16]     = *(const uint4*)src;
    *(uint4*)&tile[r][q * 16 + 8] = *(const uint4*)(src + 8);
    __syncthreads();

    union { unsigned short u[16]; uint4 v[2]; } o;
    #pragma unroll
    for (int j = 0; j < 16; ++j) o.u[j] = tile[q * 16 + j][r];
    unsigned short* dst = Vt + (size_t)(c0 + r) * T_SEQ + t0 + q * 16;
    *(uint4*)dst       = o.v[0];
    *(uint4*)(dst + 8) = o.v[1];
}

// C = A @ B^T, bf16, m97 async staging. 128x128 tile, BK=32.
template <typename TC>
__global__ __launch_bounds__(256, 2) void gemm_bt(
    const unsigned short* __restrict__ A, const unsigned short* __restrict__ B,
    TC* __restrict__ C, int M, int N, int K)
{
    __shared__ __attribute__((aligned(16))) unsigned short As[128 * 32];
    __shared__ __attribute__((aligned(16))) unsigned short Bs[128 * 32];

    const int tid  = threadIdx.x;
    const int wave = tid >> 6, lane = tid & 63;
    const int quad = lane >> 4, l16 = lane & 15;
    const int wm = wave >> 1, wn = wave & 1;
    const int m0 = blockIdx.y * 128, n0 = blockIdx.x * 128;

    const int srow = wave * 32 + (lane >> 2);
    const int scol = (lane & 3) * 8;

    f32x4 acc[4][4] = {};

    for (int k0 = 0; k0 < K; k0 += 32) {
        {
            const unsigned short* ga = A + (size_t)(m0 + srow) * K + k0 + scol;
            const unsigned short* gb = B + (size_t)(n0 + srow) * K + k0 + scol;
            unsigned short* la = As + (wave * 32) * 32;
            unsigned short* lb = Bs + (wave * 32) * 32;
            async_g2l16(ga, la);
            async_g2l16(ga + (size_t)16 * K, la + 16 * 32);
            async_g2l16(gb, lb);
            async_g2l16(gb + (size_t)16 * K, lb + 16 * 32);
        }
        __syncthreads();

        bf16x8 af[4], bf[4];
        #pragma unroll
        for (int i = 0; i < 4; ++i) {
            af[i] = ld_bf8(As + (wm * 64 + i * 16 + l16) * 32 + quad * 8);
            bf[i] = ld_bf8(Bs + (wn * 64 + i * 16 + l16) * 32 + quad * 8);
        }
        #pragma unroll
        for (int mt = 0; mt < 4; ++mt)
            #pragma unroll
            for (int nt = 0; nt < 4; ++nt)
                acc[mt][nt] = __builtin_amdgcn_mfma_f32_16x16x32_bf16(
                    af[mt], bf[nt], acc[mt][nt], 0, 0, 0);
        __syncthreads();
    }

    #pragma unroll
    for (int mt = 0; mt < 4; ++mt)
        #pragma unroll
        for (int nt = 0; nt < 4; ++nt)
            #pragma unroll
            for (int r = 0; r < 4; ++r) {
                int row = m0 + wm * 64 + mt * 16 + quad * 4 + r;
                int col = n0 + wn * 64 + nt * 16 + l16;
                store_c(C, (size_t)row * N + col, acc[mt][nt][r]);
            }
}

// Register-level quad transpose for the P fragment (replaces the LDS round-trip).
#if __has_builtin(__builtin_amdgcn_permlane32_swap) && __has_builtin(__builtin_amdgcn_permlane16_swap)
#define HAVE_PERMLANE_SWAP 1
#else
#define HAVE_PERMLANE_SWAP 0
#endif

__device__ __forceinline__ void quad_xpose_pair(uint32_t X, uint32_t Y,
                                                uint32_t& t0, uint32_t& t1) {
#if HAVE_PERMLANE_SWAP
    auto S = __builtin_amdgcn_permlane32_swap((int)X, (int)Y, false, false);
    auto T = __builtin_amdgcn_permlane16_swap((int)S[0], (int)S[1], false, false);
    t0 = (uint32_t)T[0];
    t1 = (uint32_t)T[1];
#else
    const unsigned l = threadIdx.x & 63;
    uint32_t Ys = (uint32_t)__shfl_xor((int)Y, 32, 64);
    uint32_t Xs = (uint32_t)__shfl_xor((int)X, 32, 64);
    uint32_t S0 = (l < 32) ? X : Ys;   // {A.low32, B.low32}
    uint32_t S1 = (l < 32) ? Xs : Y;   // {A.high32, B.high32}
    uint32_t S0s = (uint32_t)__shfl_xor((int)S0, 16, 64);
    uint32_t S1s = (uint32_t)__shfl_xor((int)S1, 16, 64);
    t0 = (l & 16) ? S1s : S0;
    t1 = (l & 16) ? S1 : S0s;
#endif
}

// One flash tile, 32 q-rows/wave (2 q-subtiles), max-free softmax.
// P stays in registers: quad-permutation via permlane swaps, no LDS round-trip.
template <bool MASK>
__device__ __forceinline__ void fa7_tile(
    const unsigned short* Ksb, const unsigned short* Vsb,
    const bf16x8 qf[2][2], f32x4 o[2][4], float* l_part,
    int k0, int q_abs0, int quad, int l16, int fo0, int fo1)
{
    const unsigned short* krow = Ksb + l16 * 64;
    bf16x8 kf[4][2];
    #pragma unroll
    for (int s = 0; s < 4; ++s) {
        kf[s][0] = ld_bf8(krow + s * 1024 + fo0);
        kf[s][1] = ld_bf8(krow + s * 1024 + fo1);
    }

    bf16x8 pf[2][2];
    #pragma unroll
    for (int qs = 0; qs < 2; ++qs) {
        f32x4 st[4];
        __builtin_amdgcn_s_setprio(1);
        #pragma unroll
        for (int s = 0; s < 4; ++s) {
            f32x4 z = {};
            z = __builtin_amdgcn_mfma_f32_16x16x32_bf16(kf[s][0], qf[qs][0], z, 0, 0, 0);
            st[s] = __builtin_amdgcn_mfma_f32_16x16x32_bf16(kf[s][1], qf[qs][1], z, 0, 0, 0);
        }
        __builtin_amdgcn_s_setprio(0);

        float ts = 0.f;
        #pragma unroll
        for (int s = 0; s < 4; ++s)
            #pragma unroll
            for (int r = 0; r < 4; ++r) {
                float v = st[s][r];
                if (MASK) {
                    int key = k0 + s * 16 + quad * 4 + r;
                    v = (key <= q_abs0 + qs * 16) ? v : NEG_BIG;
                }
                float e = __builtin_amdgcn_exp2f(v);   // exp2(-30000) = 0
                st[s][r] = e;
                ts += e;
            }
        l_part[qs] += ts;

        // pack P to bf16 pairs: W[s][p] = keys 16s+4*quad+2p..+1 (col = l16)
        uint32_t W[4][2];
        #pragma unroll
        for (int s = 0; s < 4; ++s) {
            W[s][0] = pk_bf16(st[s][0], st[s][1]);
            W[s][1] = pk_bf16(st[s][2], st[s][3]);
        }
        // redistribute across quads so lane holds keys 8*quad..8*quad+7 (B-operand)
        union { uint32_t w[4]; bf16x8 v; } pA, pB;
        quad_xpose_pair(W[0][0], W[1][0], pA.w[0], pA.w[2]);
        quad_xpose_pair(W[0][1], W[1][1], pA.w[1], pA.w[3]);
        quad_xpose_pair(W[2][0], W[3][0], pB.w[0], pB.w[2]);
        quad_xpose_pair(W[2][1], W[3][1], pB.w[1], pB.w[3]);
        pf[qs][0] = pA.v;   // keys  0..31
        pf[qs][1] = pB.v;   // keys 32..63
    }

    const unsigned short* vrow = Vsb + l16 * 64;
    bf16x8 vf[4][2];
    #pragma unroll
    for (int c = 0; c < 4; ++c) {
        vf[c][0] = ld_bf8(vrow + c * 1024 + fo0);
        vf[c][1] = ld_bf8(vrow + c * 1024 + fo1);
    }
    __builtin_amdgcn_s_setprio(1);
    #pragma unroll
    for (int qs = 0; qs < 2; ++qs)
        #pragma unroll
        for (int c = 0; c < 4; ++c) {
            o[qs][c] = __builtin_amdgcn_mfma_f32_16x16x32_bf16(vf[c][0], pf[qs][0], o[qs][c], 0, 0, 0);
            o[qs][c] = __builtin_amdgcn_mfma_f32_16x16x32_bf16(vf[c][1], pf[qs][1], o[qs][c], 0, 0, 0);
        }
    __builtin_amdgcn_s_setprio(0);
}

// Flash v9: flash8 + counted-vmcnt prefetch (T4). Raw s_barrier pairs per round;
// prefetch stays in flight across the barrier (no vmcnt(0) drain).
__global__ __launch_bounds__(256, 2) void flash_attn9(
    const unsigned short* __restrict__ qkv,
    const unsigned short* __restrict__ Vt,
    unsigned short* __restrict__ Y)
{
    __shared__ __attribute__((aligned(16))) unsigned short Ks[2][2][4096]; // [buf][pair-tile][64x64]
    __shared__ __attribute__((aligned(16))) unsigned short Vs[2][2][4096];

    const int tid  = threadIdx.x;
    const int wave = tid >> 6, lane = tid & 63;
    const int quad = lane >> 4, l16 = lane & 15;
    const int wq = wave >> 1, wk = wave & 1;

    // LPT order: first 512 blocks = qb 63..32 (longest first), then 31..0
    const int bi = blockIdx.x;
    const int h  = bi & 15;
    const int qb = (bi < 512) ? (63 - (bi >> 4)) : (31 - ((bi - 512) >> 4));

    const int q0w    = qb * 64 + wq * 32;
    const int q_abs0 = q0w + l16;              // qs=0 row; qs=1 adds 16
    const int sw  = l16 & 7;
    const int fo0 = (quad ^ sw) * 8;
    const int fo1 = ((quad + 4) ^ sw) * 8;

    // Q fragments (B-operand), prescaled by 0.125*log2(e); 2 q-subtiles
    bf16x8 qf[2][2];
    {
        const float QS = 0.125f * 1.44269504f;
        #pragma unroll
        for (int qs = 0; qs < 2; ++qs) {
            const unsigned short* qp =
                qkv + (size_t)(q0w + qs * 16 + l16) * C3 + h * HD + quad * 8;
            bf16x8 a = ld_bf8(qp), b = ld_bf8(qp + 32);
            #pragma unroll
            for (int i = 0; i < 8; ++i) {
                qf[qs][0][i] = (__bf16)((float)a[i] * QS);
                qf[qs][1][i] = (__bf16)((float)b[i] * QS);
            }
        }
    }

    // Staging: per round, 4 waves stage a PAIR of K tiles + PAIR of V tiles.
    // wave -> (st_tile = wq, st_half = wk): 32 K rows + 32 V rows in 4+4 calls.
    const int srow   = lane >> 3;              // 0..7
    const int schunk = (lane & 7) ^ srow;      // XOR swizzle chunk
    const unsigned short* kp =
        qkv + (size_t)(wq * 64 + wk * 32 + srow) * C3 + C_DIM + h * HD + schunk * 8;
    const unsigned short* vp =
        Vt + (size_t)(h * HD + wk * 32 + srow) * T_SEQ + wq * 64 + schunk * 8;
    unsigned short* lk = &Ks[0][wq][(wk * 32) * 64];
    unsigned short* lv = &Vs[0][wq][(wk * 32) * 64];
    const int lds_db = 2 * 4096;               // shorts between buf0/buf1 same tile
    const size_t kstep = (size_t)8 * C3;
    const size_t vstep = (size_t)8 * T_SEQ;

    auto stage = [&](int b) {
        #pragma unroll
        for (int jj = 0; jj < 4; ++jj) {
            async_g2l16(kp + jj * kstep, lk + b * lds_db + jj * 8 * 64);
            async_g2l16(vp + jj * vstep, lv + b * lds_db + jj * 8 * 64);
        }
    };

    f32x4 o[2][4] = {};
    float l_part[2] = {0.f, 0.f};

    const int nt = qb + 1;
    const int R  = (nt + 1) >> 1;
    stage(0);
    kp += (size_t)128 * C3; vp += 128;

    for (int r = 0; r < R; ++r) {
        const int b = r & 1;
        // barrier A: all waves done reading buffer 1-b (round r-1 ds_reads consumed)
        __builtin_amdgcn_s_barrier();
        if (r + 1 < R) {
            stage(1 - b);                      // outstanding: 8 (buf b) + 8 (new)
            kp += (size_t)128 * C3; vp += 128;
            asm volatile("s_waitcnt vmcnt(8)" ::: "memory");   // buf b landed (mine)
        } else {
            asm volatile("s_waitcnt vmcnt(0)" ::: "memory");
        }
        __builtin_amdgcn_sched_barrier(0);
        // barrier B: everyone's buf-b loads landed -> safe to read
        __builtin_amdgcn_s_barrier();

        const int t = 2 * r + wk;
        if (t < nt) {
            if (t == nt - 1)
                fa7_tile<true>(&Ks[b][wk][0], &Vs[b][wk][0], qf, o, l_part,
                               t * 64, q_abs0, quad, l16, fo0, fo1);
            else
                fa7_tile<false>(&Ks[b][wk][0], &Vs[b][wk][0], qf, o, l_part,
                                t * 64, q_abs0, quad, l16, fo0, fo1);
        }
    }

    // Cross-wk reduction through LDS (max-free softmax: partials just add).
    __syncthreads();
    float* red  = (float*)&Ks[0][0][0];        // 16 KB used
    float* lred = (float*)&Vs[0][0][0];        // 1 KB used
    if (wk == 1) {
        #pragma unroll
        for (int qs = 0; qs < 2; ++qs)
            #pragma unroll
            for (int c = 0; c < 4; ++c)
                *(f32x4*)&red[((wq * 8 + qs * 4 + c) * 64 + lane) * 4] = o[qs][c];
        lred[wq * 128 + lane * 2 + 0] = l_part[0];
        lred[wq * 128 + lane * 2 + 1] = l_part[1];
    }
    __syncthreads();
    if (wk == 0) {
        #pragma unroll
        for (int qs = 0; qs < 2; ++qs) {
            #pragma unroll
            for (int c = 0; c < 4; ++c) {
                f32x4 p = *(f32x4*)&red[((wq * 8 + qs * 4 + c) * 64 + lane) * 4];
                o[qs][c] += p;
            }
            l_part[qs] += lred[wq * 128 + lane * 2 + qs];
        }

        #pragma unroll
        for (int qs = 0; qs < 2; ++qs) {
            float l = l_part[qs];
            l += __shfl_xor(l, 16, 64);
            l += __shfl_xor(l, 32, 64);
            float inv_l = 1.f / l;
            #pragma unroll
            for (int c = 0; c < 4; ++c) {
                union { uint32_t w[2]; uint2 q; } t;
                t.w[0] = pk_bf16(o[qs][c][0] * inv_l, o[qs][c][1] * inv_l);
                t.w[1] = pk_bf16(o[qs][c][2] * inv_l, o[qs][c][3] * inv_l);
                *(uint2*)(Y + (size_t)(q_abs0 + qs * 16) * C_DIM + h * HD + c * 16 + quad * 4) = t.q;
            }
        }
    }
}

extern "C" void kernel_launch(void* const* d_in, const int* in_sizes, int n_in,
                              void* d_out, int out_size, void* d_ws, size_t ws_size,
                              hipStream_t stream) {
    const float* x      = (const float*)d_in[0];
    const float* w_attn = (const float*)d_in[1];
    const float* w_proj = (const float*)d_in[2];
    float* out = (float*)d_out;

    unsigned short* qkv = (unsigned short*)d_ws;            // [4096,3072] bf16
    unsigned short* xb  = qkv + (size_t)T_SEQ * C3;         // [4096,1024] bf16
    unsigned short* y   = xb;                               // alias after gemm1
    unsigned short* wpb = qkv;                              // alias after flash
    unsigned short* Vt  = (unsigned short*)d_out;           // [1024][4096] bf16
    unsigned short* wab = Vt + (size_t)C_DIM * T_SEQ;       // [3072,1024] bf16

    cvt_xw<<<(T_SEQ * C_DIM + C3 * C_DIM) / 8 / 256, 256, 0, stream>>>(x, w_attn, xb, wab);

    gemm_bt<unsigned short>
        <<<dim3(C3 / 128, T_SEQ / 128), 256, 0, stream>>>(xb, wab, qkv, T_SEQ, C3, C_DIM);

    v_transpose<<<dim3(T_SEQ / 64, C_DIM / 64), 256, 0, stream>>>(qkv, Vt);

    flash_attn9<<<dim3(1024), 256, 0, stream>>>(qkv, Vt, y);

    cvt_f32_bf16<<<(C_DIM * C_DIM / 8 + 255) / 256, 256, 0, stream>>>(w_proj, wpb, C_DIM * C_DIM);
    gemm_bt<float>
        <<<dim3(C_DIM / 128, T_SEQ / 128), 256, 0, stream>>>(y, wpb, out, T_SEQ, C_DIM, C_DIM);
}

// Round 5
// 194.775 us; speedup vs baseline: 1.0303x; 1.0303x over previous
//
#include <hip/hip_runtime.h>
#include <hip/hip_bf16.h>
#include <stdint.h>

typedef __bf16 bf16x8 __attribute__((ext_vector_type(8)));
typedef float f32x4 __attribute__((ext_vector_type(4)));

#define T_SEQ 4096
#define C_DIM 1024
#define H_NUM 16
#define HD 64
#define C3 3072
#define NEG_BIG (-30000.0f)

__device__ __forceinline__ unsigned short f2bf(float f) {
    uint32_t u = __builtin_bit_cast(uint32_t, f);
    u += 0x7fffu + ((u >> 16) & 1u);
    return (unsigned short)(u >> 16);
}

__device__ __forceinline__ uint32_t pk_bf16(float a, float b) {
    __hip_bfloat162 h = __float22bfloat162_rn(float2{a, b});
    uint32_t u;
    __builtin_memcpy(&u, &h, sizeof(u));
    return u;
}

__device__ __forceinline__ bf16x8 ld_bf8(const unsigned short* p) {
    return *reinterpret_cast<const bf16x8*>(p);
}

__device__ __forceinline__ void async_g2l16(const unsigned short* g, unsigned short* l) {
    __builtin_amdgcn_global_load_lds(
        (const __attribute__((address_space(1))) void*)g,
        (__attribute__((address_space(3))) void*)l, 16, 0, 0);
}

__device__ __forceinline__ void store_c(unsigned short* C, size_t idx, float v) { C[idx] = f2bf(v); }
__device__ __forceinline__ void store_c(float* C, size_t idx, float v)          { C[idx] = v; }

__device__ __forceinline__ void cvt8(const float* src, unsigned short* dst) {
    float4 f0 = *(const float4*)src;
    float4 f1 = *(const float4*)(src + 4);
    union { uint32_t w[4]; uint4 q; } t;
    t.w[0] = pk_bf16(f0.x, f0.y);
    t.w[1] = pk_bf16(f0.z, f0.w);
    t.w[2] = pk_bf16(f1.x, f1.y);
    t.w[3] = pk_bf16(f1.z, f1.w);
    *(uint4*)dst = t.q;
}

// x, w_attn, (optionally w_proj) fp32 -> bf16 in one launch (concatenated index space)
__global__ void cvt_all(const float* __restrict__ x, const float* __restrict__ wa,
                        const float* __restrict__ wp,
                        unsigned short* __restrict__ xb, unsigned short* __restrict__ wab,
                        unsigned short* __restrict__ wpb) {
    int i = (blockIdx.x * blockDim.x + threadIdx.x) * 8;
    if (i < T_SEQ * C_DIM) { cvt8(x + i, xb + i); return; }
    i -= T_SEQ * C_DIM;
    if (i < C3 * C_DIM) { cvt8(wa + i, wab + i); return; }
    i -= C3 * C_DIM;
    if (wpb != nullptr && i < C_DIM * C_DIM) cvt8(wp + i, wpb + i);
}

__global__ void cvt_f32_bf16(const float* __restrict__ src, unsigned short* __restrict__ dst, int n) {
    int i = (blockIdx.x * blockDim.x + threadIdx.x) * 8;
    if (i >= n) return;
    cvt8(src + i, dst + i);
}

// V part of qkv [T][3C] -> Vt [C][T], 64x64 tiles through padded LDS.
__global__ __launch_bounds__(256) void v_transpose(
    const unsigned short* __restrict__ qkv, unsigned short* __restrict__ Vt)
{
    __shared__ unsigned short tile[64][72];
    const int t0 = blockIdx.x * 64, c0 = blockIdx.y * 64;
    const int r = threadIdx.x >> 2, q = threadIdx.x & 3;

    const unsigned short* src = qkv + (size_t)(t0 + r) * C3 + 2 * C_DIM + c0 + q * 16;
    *(uint4*)&tile[r][q * 16]     = *(const uint4*)src;
    *(uint4*)&tile[r][q * 16 + 8] = *(const uint4*)(src + 8);
    __syncthreads();

    union { unsigned short u[16]; uint4 v[2]; } o;
    #pragma unroll
    for (int j = 0; j < 16; ++j) o.u[j] = tile[q * 16 + j][r];
    unsigned short* dst = Vt + (size_t)(c0 + r) * T_SEQ + t0 + q * 16;
    *(uint4*)dst       = o.v[0];
    *(uint4*)(dst + 8) = o.v[1];
}

// C = A @ B^T, bf16, m97 async staging. Tile BM x 128, BK=32.
// BM=128: 256 thr / 4 waves (2x2). BM=64: 128 thr / 2 waves (1x2) -> more,
// smaller blocks so multiple blocks/CU overlap each other's barrier drains.
template <int BM, typename TC>
__global__ __launch_bounds__(BM * 2, (BM == 128) ? 2 : 3) void gemm_bt(
    const unsigned short* __restrict__ A, const unsigned short* __restrict__ B,
    TC* __restrict__ C, int M, int N, int K)
{
    __shared__ __attribute__((aligned(16))) unsigned short As[BM * 32];
    __shared__ __attribute__((aligned(16))) unsigned short Bs[128 * 32];

    const int tid  = threadIdx.x;
    const int wave = tid >> 6, lane = tid & 63;
    const int quad = lane >> 4, l16 = lane & 15;
    const int wm = (BM == 128) ? (wave >> 1) : 0;
    const int wn = (BM == 128) ? (wave & 1) : wave;
    const int m0 = blockIdx.y * BM, n0 = blockIdx.x * 128;

    const int sr   = lane >> 2;        // 0..15
    const int scol = (lane & 3) * 8;

    f32x4 acc[4][4] = {};

    for (int k0 = 0; k0 < K; k0 += 32) {
        if constexpr (BM == 128) {
            const unsigned short* ga = A + (size_t)(m0 + wave * 32 + sr) * K + k0 + scol;
            const unsigned short* gb = B + (size_t)(n0 + wave * 32 + sr) * K + k0 + scol;
            unsigned short* la = As + (wave * 32) * 32;
            unsigned short* lb = Bs + (wave * 32) * 32;
            async_g2l16(ga, la);
            async_g2l16(ga + (size_t)16 * K, la + 16 * 32);
            async_g2l16(gb, lb);
            async_g2l16(gb + (size_t)16 * K, lb + 16 * 32);
        } else {
            // 2 waves: A 64 rows (32/wave), B 128 rows (64/wave)
            const unsigned short* ga = A + (size_t)(m0 + wave * 32 + sr) * K + k0 + scol;
            unsigned short* la = As + (wave * 32) * 32;
            async_g2l16(ga, la);
            async_g2l16(ga + (size_t)16 * K, la + 16 * 32);
            const unsigned short* gb = B + (size_t)(n0 + wave * 64 + sr) * K + k0 + scol;
            unsigned short* lb = Bs + (wave * 64) * 32;
            async_g2l16(gb, lb);
            async_g2l16(gb + (size_t)16 * K, lb + 16 * 32);
            async_g2l16(gb + (size_t)32 * K, lb + 32 * 32);
            async_g2l16(gb + (size_t)48 * K, lb + 48 * 32);
        }
        __syncthreads();

        bf16x8 af[4], bf[4];
        #pragma unroll
        for (int i = 0; i < 4; ++i) {
            af[i] = ld_bf8(As + (wm * 64 + i * 16 + l16) * 32 + quad * 8);
            bf[i] = ld_bf8(Bs + (wn * 64 + i * 16 + l16) * 32 + quad * 8);
        }
        #pragma unroll
        for (int mt = 0; mt < 4; ++mt)
            #pragma unroll
            for (int nt = 0; nt < 4; ++nt)
                acc[mt][nt] = __builtin_amdgcn_mfma_f32_16x16x32_bf16(
                    af[mt], bf[nt], acc[mt][nt], 0, 0, 0);
        __syncthreads();
    }

    #pragma unroll
    for (int mt = 0; mt < 4; ++mt)
        #pragma unroll
        for (int nt = 0; nt < 4; ++nt)
            #pragma unroll
            for (int r = 0; r < 4; ++r) {
                int row = m0 + wm * 64 + mt * 16 + quad * 4 + r;
                int col = n0 + wn * 64 + nt * 16 + l16;
                store_c(C, (size_t)row * N + col, acc[mt][nt][r]);
            }
}

// Register-level quad transpose for the P fragment (replaces the LDS round-trip).
#if __has_builtin(__builtin_amdgcn_permlane32_swap) && __has_builtin(__builtin_amdgcn_permlane16_swap)
#define HAVE_PERMLANE_SWAP 1
#else
#define HAVE_PERMLANE_SWAP 0
#endif

__device__ __forceinline__ void quad_xpose_pair(uint32_t X, uint32_t Y,
                                                uint32_t& t0, uint32_t& t1) {
#if HAVE_PERMLANE_SWAP
    auto S = __builtin_amdgcn_permlane32_swap((int)X, (int)Y, false, false);
    auto T = __builtin_amdgcn_permlane16_swap((int)S[0], (int)S[1], false, false);
    t0 = (uint32_t)T[0];
    t1 = (uint32_t)T[1];
#else
    const unsigned l = threadIdx.x & 63;
    uint32_t Ys = (uint32_t)__shfl_xor((int)Y, 32, 64);
    uint32_t Xs = (uint32_t)__shfl_xor((int)X, 32, 64);
    uint32_t S0 = (l < 32) ? X : Ys;   // {A.low32, B.low32}
    uint32_t S1 = (l < 32) ? Xs : Y;   // {A.high32, B.high32}
    uint32_t S0s = (uint32_t)__shfl_xor((int)S0, 16, 64);
    uint32_t S1s = (uint32_t)__shfl_xor((int)S1, 16, 64);
    t0 = (l & 16) ? S1s : S0;
    t1 = (l & 16) ? S1 : S0s;
#endif
}

// One flash tile, 32 q-rows/wave (2 q-subtiles), max-free softmax.
// P stays in registers: quad-permutation via permlane swaps, no LDS round-trip.
template <bool MASK>
__device__ __forceinline__ void fa7_tile(
    const unsigned short* Ksb, const unsigned short* Vsb,
    const bf16x8 qf[2][2], f32x4 o[2][4], float* l_part,
    int k0, int q_abs0, int quad, int l16, int fo0, int fo1)
{
    const unsigned short* krow = Ksb + l16 * 64;
    bf16x8 kf[4][2];
    #pragma unroll
    for (int s = 0; s < 4; ++s) {
        kf[s][0] = ld_bf8(krow + s * 1024 + fo0);
        kf[s][1] = ld_bf8(krow + s * 1024 + fo1);
    }

    bf16x8 pf[2][2];
    #pragma unroll
    for (int qs = 0; qs < 2; ++qs) {
        f32x4 st[4];
        __builtin_amdgcn_s_setprio(1);
        #pragma unroll
        for (int s = 0; s < 4; ++s) {
            f32x4 z = {};
            z = __builtin_amdgcn_mfma_f32_16x16x32_bf16(kf[s][0], qf[qs][0], z, 0, 0, 0);
            st[s] = __builtin_amdgcn_mfma_f32_16x16x32_bf16(kf[s][1], qf[qs][1], z, 0, 0, 0);
        }
        __builtin_amdgcn_s_setprio(0);

        float ts = 0.f;
        #pragma unroll
        for (int s = 0; s < 4; ++s)
            #pragma unroll
            for (int r = 0; r < 4; ++r) {
                float v = st[s][r];
                if (MASK) {
                    int key = k0 + s * 16 + quad * 4 + r;
                    v = (key <= q_abs0 + qs * 16) ? v : NEG_BIG;
                }
                float e = __builtin_amdgcn_exp2f(v);   // exp2(-30000) = 0
                st[s][r] = e;
                ts += e;
            }
        l_part[qs] += ts;

        // pack P to bf16 pairs: W[s][p] = keys 16s+4*quad+2p..+1 (col = l16)
        uint32_t W[4][2];
        #pragma unroll
        for (int s = 0; s < 4; ++s) {
            W[s][0] = pk_bf16(st[s][0], st[s][1]);
            W[s][1] = pk_bf16(st[s][2], st[s][3]);
        }
        // redistribute across quads so lane holds keys 8*quad..8*quad+7 (B-operand)
        union { uint32_t w[4]; bf16x8 v; } pA, pB;
        quad_xpose_pair(W[0][0], W[1][0], pA.w[0], pA.w[2]);
        quad_xpose_pair(W[0][1], W[1][1], pA.w[1], pA.w[3]);
        quad_xpose_pair(W[2][0], W[3][0], pB.w[0], pB.w[2]);
        quad_xpose_pair(W[2][1], W[3][1], pB.w[1], pB.w[3]);
        pf[qs][0] = pA.v;   // keys  0..31
        pf[qs][1] = pB.v;   // keys 32..63
    }

    const unsigned short* vrow = Vsb + l16 * 64;
    bf16x8 vf[4][2];
    #pragma unroll
    for (int c = 0; c < 4; ++c) {
        vf[c][0] = ld_bf8(vrow + c * 1024 + fo0);
        vf[c][1] = ld_bf8(vrow + c * 1024 + fo1);
    }
    __builtin_amdgcn_s_setprio(1);
    #pragma unroll
    for (int qs = 0; qs < 2; ++qs)
        #pragma unroll
        for (int c = 0; c < 4; ++c) {
            o[qs][c] = __builtin_amdgcn_mfma_f32_16x16x32_bf16(vf[c][0], pf[qs][0], o[qs][c], 0, 0, 0);
            o[qs][c] = __builtin_amdgcn_mfma_f32_16x16x32_bf16(vf[c][1], pf[qs][1], o[qs][c], 0, 0, 0);
        }
    __builtin_amdgcn_s_setprio(0);
}

// Flash v8 (reverted R3 structure): 4-wave blocks (wq x wk = 2x2), 64 q-rows,
// intra-block key split (max-free softmax => partials add), paired-tile dbuf
// staging (64KB LDS, 2 blocks/CU), LPT block order.
__global__ __launch_bounds__(256, 2) void flash_attn8(
    const unsigned short* __restrict__ qkv,
    const unsigned short* __restrict__ Vt,
    unsigned short* __restrict__ Y)
{
    __shared__ __attribute__((aligned(16))) unsigned short Ks[2][2][4096]; // [buf][pair-tile][64x64]
    __shared__ __attribute__((aligned(16))) unsigned short Vs[2][2][4096];

    const int tid  = threadIdx.x;
    const int wave = tid >> 6, lane = tid & 63;
    const int quad = lane >> 4, l16 = lane & 15;
    const int wq = wave >> 1, wk = wave & 1;

    // LPT order: first 512 blocks = qb 63..32 (longest first), then 31..0
    const int bi = blockIdx.x;
    const int h  = bi & 15;
    const int qb = (bi < 512) ? (63 - (bi >> 4)) : (31 - ((bi - 512) >> 4));

    const int q0w    = qb * 64 + wq * 32;
    const int q_abs0 = q0w + l16;              // qs=0 row; qs=1 adds 16
    const int sw  = l16 & 7;
    const int fo0 = (quad ^ sw) * 8;
    const int fo1 = ((quad + 4) ^ sw) * 8;

    // Q fragments (B-operand), prescaled by 0.125*log2(e); 2 q-subtiles
    bf16x8 qf[2][2];
    {
        const float QS = 0.125f * 1.44269504f;
        #pragma unroll
        for (int qs = 0; qs < 2; ++qs) {
            const unsigned short* qp =
                qkv + (size_t)(q0w + qs * 16 + l16) * C3 + h * HD + quad * 8;
            bf16x8 a = ld_bf8(qp), b = ld_bf8(qp + 32);
            #pragma unroll
            for (int i = 0; i < 8; ++i) {
                qf[qs][0][i] = (__bf16)((float)a[i] * QS);
                qf[qs][1][i] = (__bf16)((float)b[i] * QS);
            }
        }
    }

    // Staging: per round, 4 waves stage a PAIR of K tiles + PAIR of V tiles.
    // wave -> (st_tile = wq, st_half = wk): 32 K rows + 32 V rows in 4+4 calls.
    const int srow   = lane >> 3;              // 0..7
    const int schunk = (lane & 7) ^ srow;      // XOR swizzle chunk
    const unsigned short* kp =
        qkv + (size_t)(wq * 64 + wk * 32 + srow) * C3 + C_DIM + h * HD + schunk * 8;
    const unsigned short* vp =
        Vt + (size_t)(h * HD + wk * 32 + srow) * T_SEQ + wq * 64 + schunk * 8;
    unsigned short* lk = &Ks[0][wq][(wk * 32) * 64];
    unsigned short* lv = &Vs[0][wq][(wk * 32) * 64];
    const int lds_db = 2 * 4096;               // shorts between buf0/buf1 same tile
    const size_t kstep = (size_t)8 * C3;
    const size_t vstep = (size_t)8 * T_SEQ;

    auto stage = [&](int b) {
        #pragma unroll
        for (int jj = 0; jj < 4; ++jj) {
            async_g2l16(kp + jj * kstep, lk + b * lds_db + jj * 8 * 64);
            async_g2l16(vp + jj * vstep, lv + b * lds_db + jj * 8 * 64);
        }
    };

    f32x4 o[2][4] = {};
    float l_part[2] = {0.f, 0.f};

    const int nt = qb + 1;
    const int R  = (nt + 1) >> 1;
    stage(0);
    kp += (size_t)128 * C3; vp += 128;

    for (int r = 0; r < R; ++r) {
        __syncthreads();
        const int b = r & 1;
        if (r + 1 < R) {
            stage(1 - b);
            kp += (size_t)128 * C3; vp += 128;
        }
        const int t = 2 * r + wk;
        if (t < nt) {
            if (t == nt - 1)
                fa7_tile<true>(&Ks[b][wk][0], &Vs[b][wk][0], qf, o, l_part,
                               t * 64, q_abs0, quad, l16, fo0, fo1);
            else
                fa7_tile<false>(&Ks[b][wk][0], &Vs[b][wk][0], qf, o, l_part,
                                t * 64, q_abs0, quad, l16, fo0, fo1);
        }
    }

    // Cross-wk reduction through LDS (max-free softmax: partials just add).
    __syncthreads();
    float* red  = (float*)&Ks[0][0][0];        // 16 KB used
    float* lred = (float*)&Vs[0][0][0];        // 1 KB used
    if (wk == 1) {
        #pragma unroll
        for (int qs = 0; qs < 2; ++qs)
            #pragma unroll
            for (int c = 0; c < 4; ++c)
                *(f32x4*)&red[((wq * 8 + qs * 4 + c) * 64 + lane) * 4] = o[qs][c];
        lred[wq * 128 + lane * 2 + 0] = l_part[0];
        lred[wq * 128 + lane * 2 + 1] = l_part[1];
    }
    __syncthreads();
    if (wk == 0) {
        #pragma unroll
        for (int qs = 0; qs < 2; ++qs) {
            #pragma unroll
            for (int c = 0; c < 4; ++c) {
                f32x4 p = *(f32x4*)&red[((wq * 8 + qs * 4 + c) * 64 + lane) * 4];
                o[qs][c] += p;
            }
            l_part[qs] += lred[wq * 128 + lane * 2 + qs];
        }

        #pragma unroll
        for (int qs = 0; qs < 2; ++qs) {
            float l = l_part[qs];
            l += __shfl_xor(l, 16, 64);
            l += __shfl_xor(l, 32, 64);
            float inv_l = 1.f / l;
            #pragma unroll
            for (int c = 0; c < 4; ++c) {
                union { uint32_t w[2]; uint2 q; } t;
                t.w[0] = pk_bf16(o[qs][c][0] * inv_l, o[qs][c][1] * inv_l);
                t.w[1] = pk_bf16(o[qs][c][2] * inv_l, o[qs][c][3] * inv_l);
                *(uint2*)(Y + (size_t)(q_abs0 + qs * 16) * C_DIM + h * HD + c * 16 + quad * 4) = t.q;
            }
        }
    }
}

extern "C" void kernel_launch(void* const* d_in, const int* in_sizes, int n_in,
                              void* d_out, int out_size, void* d_ws, size_t ws_size,
                              hipStream_t stream) {
    const float* x      = (const float*)d_in[0];
    const float* w_attn = (const float*)d_in[1];
    const float* w_proj = (const float*)d_in[2];
    float* out = (float*)d_out;

    unsigned short* qkv = (unsigned short*)d_ws;            // [4096,3072] bf16
    unsigned short* xb  = qkv + (size_t)T_SEQ * C3;         // [4096,1024] bf16
    unsigned short* y   = xb;                               // alias after gemm1
    unsigned short* Vt  = (unsigned short*)d_out;           // [1024][4096] bf16
    unsigned short* wab = Vt + (size_t)C_DIM * T_SEQ;       // [3072,1024] bf16

    // w_proj bf16 placement: after xb if workspace allows (enables fused cvt,
    // one fewer launch); else alias qkv and convert after flash.
    const size_t need = ((size_t)T_SEQ * C3 + (size_t)T_SEQ * C_DIM +
                         (size_t)C_DIM * C_DIM) * sizeof(unsigned short);
    const bool fuse_wp = ws_size >= need;
    unsigned short* wpb = fuse_wp ? (xb + (size_t)T_SEQ * C_DIM)
                                  : qkv;

    if (fuse_wp) {
        const int n8 = (T_SEQ * C_DIM + C3 * C_DIM + C_DIM * C_DIM) / 8;
        cvt_all<<<n8 / 256, 256, 0, stream>>>(x, w_attn, w_proj, xb, wab, wpb);
    } else {
        const int n8 = (T_SEQ * C_DIM + C3 * C_DIM) / 8;
        cvt_all<<<n8 / 256, 256, 0, stream>>>(x, w_attn, nullptr, xb, wab, nullptr);
    }

    gemm_bt<128, unsigned short>
        <<<dim3(C3 / 128, T_SEQ / 128), 256, 0, stream>>>(xb, wab, qkv, T_SEQ, C3, C_DIM);

    v_transpose<<<dim3(T_SEQ / 64, C_DIM / 64), 256, 0, stream>>>(qkv, Vt);

    flash_attn8<<<dim3(1024), 256, 0, stream>>>(qkv, Vt, y);

    if (!fuse_wp) {
        cvt_f32_bf16<<<(C_DIM * C_DIM / 8 + 255) / 256, 256, 0, stream>>>(w_proj, wpb, C_DIM * C_DIM);
    }

    gemm_bt<64, float>
        <<<dim3(C_DIM / 128, T_SEQ / 64), 128, 0, stream>>>(y, wpb, out, T_SEQ, C_DIM, C_DIM);
}